// Round 7
// baseline (309.503 us; speedup 1.0000x reference)
//
#include <hip/hip_runtime.h>
#include <hip/hip_bf16.h>

#define DM 384
#define NH 6
#define DH 64
#define CD 768
#define NBATCH 4
#define IMH 128
#define IMW 128
#define HEADPIX (IMH*IMW)          // 16384
#define NPIX (NBATCH*IMH*IMW)      // 65536
#define PLANE ((size_t)NPIX*DM)    // 25165824 elements per q/k/v plane
#define KS 7
#define EPSF 1e-6f

typedef __attribute__((ext_vector_type(8))) short bf16x8v;
typedef __attribute__((ext_vector_type(4))) short bf16x4v;
typedef __attribute__((ext_vector_type(4))) float f32x4v;
typedef __attribute__((ext_vector_type(4))) unsigned short u16x4;

#define GLOAD_LDS16(g, l) __builtin_amdgcn_global_load_lds( \
    (const __attribute__((address_space(1))) void*)(g), \
    (__attribute__((address_space(3))) void*)(l), 16, 0, 0)

// hardware transpose read of a 4x16-bf16 subtile: group lanes at base+fr*8,
// lane fr elem j <- tile[row j][col fr]   (verified on HW in R4)
#define TR64(dst, p, imm) asm volatile("ds_read_b64_tr_b16 %0, %1 offset:" #imm \
    : "=v"(dst) : "v"((const __attribute__((address_space(3))) char*)(p)))

__device__ __forceinline__ unsigned short f2bf(float f){
    __hip_bfloat16 h = __float2bfloat16(f);
    return *reinterpret_cast<unsigned short*>(&h);
}
__device__ __forceinline__ bf16x8v cat8(bf16x4v lo, bf16x4v hi){
    bf16x8v r;
    r[0]=lo[0]; r[1]=lo[1]; r[2]=lo[2]; r[3]=lo[3];
    r[4]=hi[0]; r[5]=hi[1]; r[6]=hi[2]; r[7]=hi[3];
    return r;
}

// swizzled LDS fragment reads: tile stored [row][128B], byte col ^= (row&7)<<4
__device__ __forceinline__ bf16x8v frag8(const __hip_bfloat16* base, int row, int kelem){
    int byteoff = row*128 + ((kelem*2) ^ ((row & 7) << 4));
    return *(const bf16x8v*)((const char*)base + byteoff);
}
// BK=32 variant: rows are 64B; slot (16B) XOR (row>>1)&3 -> 2 lanes/bank (free)
__device__ __forceinline__ bf16x8v frag32(const char* base, int row, int kbyte){
    int byteoff = row*64 + (kbyte ^ (((row >> 1) & 3) << 4));
    return *(const bf16x8v*)(base + byteoff);
}

// ---------------- K1: s_cond = cond @ w_cond + 1 (split-K over 4 waves) ----------------
__global__ __launch_bounds__(256) void k_cond(const float* __restrict__ cond,
                                              const float* __restrict__ wc,
                                              float* __restrict__ sc){
    __shared__ float red[4][64];
    const int b = blockIdx.x;           // 24 = 4 n * 6 j-chunks
    const int n = b / 6, j0 = (b - n*6) * 64;
    const int lane = threadIdx.x & 63, wave = threadIdx.x >> 6;
    const float* cr = cond + n*CD + wave*192;
    const float* wp = wc + (size_t)(wave*192)*DM + j0 + lane;
    float acc = 0.f;
    #pragma unroll 4
    for (int i = 0; i < 192; ++i) acc += cr[i] * wp[(size_t)i*DM];
    red[wave][lane] = acc;
    __syncthreads();
    if (threadIdx.x < 64) {
        float s = red[0][lane] + red[1][lane] + red[2][lane] + red[3][lane];
        sc[n*DM + j0 + lane] = s + 1.0f;
    }
}

// ---------------- K2: xb = bf16(x * rsqrt(mean(x^2)+eps) * s_cond) ----------------
__global__ __launch_bounds__(256) void k_xscale(const float* __restrict__ x,
                                                const float* __restrict__ sc,
                                                __hip_bfloat16* __restrict__ xb){
    int row  = blockIdx.x*4 + (threadIdx.x>>6);
    int lane = threadIdx.x & 63;
    int n    = row >> 14;
    const float* xr  = x + (size_t)row*DM;
    const float* scp = sc + n*DM;
    float v[6];
    float s = 0.f;
    #pragma unroll
    for (int i=0;i<6;++i){ v[i] = xr[i*64+lane]; s += v[i]*v[i]; }
    #pragma unroll
    for (int o=32;o;o>>=1) s += __shfl_xor(s,o);
    float r = rsqrtf(s*(1.0f/DM) + EPSF);
    #pragma unroll
    for (int i=0;i<6;++i)
        xb[(size_t)row*DM + i*64+lane] = __float2bfloat16(v[i]*r*scp[i*64+lane]);
}

// ---------------- weight converts: bf16, transposed to [N][K] ----------------
__global__ void k_cvtwq(const float* __restrict__ wq, __hip_bfloat16* __restrict__ wqb){
    int id = blockIdx.x*256 + threadIdx.x;          // 1152*384
    if (id >= 3*DM*DM) return;
    int nn = id / DM, kk = id - nn*DM;
    wqb[id] = __float2bfloat16(wq[(size_t)kk*(3*DM) + nn]);
}
__global__ void k_cvtwo(const float* __restrict__ wo, __hip_bfloat16* __restrict__ wob){
    int id = blockIdx.x*256 + threadIdx.x;          // 384*384
    if (id >= DM*DM) return;
    int nn = id / DM, kk = id - nn*DM;
    wob[id] = __float2bfloat16(wo[(size_t)kk*DM + nn]);
}

// ---------------- K3: qkv = xb @ w_qkv via bf16 MFMA (transposed C); fused qk-norm + rotary ----------------
// BK=32: A and B double-buffered at 2x8KB each -> 32 KB LDS -> 4-5 blocks/CU.
// Staging: per buffer 512 16B-chunks; chunk ch -> row=ch>>2, slot=ch&3,
// source k-offset = (slot ^ ((row>>1)&3))*8 elems (pre-swizzled source, linear dest).
// acc[i][ni]: output ROW = weight col j = j0 + wc + i*16 + fg*4 + r (dim),
//             output COL = pixel     m = m0 + wr + ni*16 + fr
__global__ __launch_bounds__(256) void k_qkv_mfma(
    const __hip_bfloat16* __restrict__ xb, const __hip_bfloat16* __restrict__ wqb,
    const float* __restrict__ pos, const float* __restrict__ freqs,
    const float* __restrict__ scale, __hip_bfloat16* __restrict__ qkv)
{
    __shared__ char As[2*8192];
    __shared__ char Bs[2*8192];
    const int t    = threadIdx.x;
    const int lane = t & 63;
    const int wave = t >> 6;
    // XCD-bijective swizzle: 4608 blocks = 8 XCDs x 576; j fastest within chunk
    const int swzb = (blockIdx.x & 7)*576 + (blockIdx.x >> 3);
    const int jb = swzb % 9;
    const int mb = swzb / 9;
    const int j0 = jb*128, m0 = mb*128;
    const int n  = m0 >> 14;
    const int wr = (wave >> 1) * 64;
    const int wc = (wave & 1) * 64;
    const int fr = lane & 15;
    const int fg = lane >> 4;

    f32x4v acc[4][4] = {};

#define STAGE_QKV(buf, k0) \
    { _Pragma("unroll") \
      for (int i = 0; i < 2; ++i) { \
        int ch  = i*256 + t; \
        int row = ch >> 2; \
        int sc_ = ((ch & 3) ^ ((row >> 1) & 3)) << 3; \
        GLOAD_LDS16(xb  + (size_t)(m0 + row)*DM + (k0) + sc_, \
                    As + (buf)*8192 + (i*256 + (wave<<6))*16); \
        GLOAD_LDS16(wqb + (size_t)(j0 + row)*DM + (k0) + sc_, \
                    Bs + (buf)*8192 + (i*256 + (wave<<6))*16); \
      } }

    // 2-phase pipeline: stage(next) -> counted vmcnt -> barrier -> compute(cur) -> barrier
    STAGE_QKV(0, 0)
    #pragma unroll
    for (int kt = 0; kt < 12; ++kt) {
        const int cur = kt & 1;
        if (kt < 11) {
            STAGE_QKV(cur ^ 1, (kt+1)*32)
            asm volatile("s_waitcnt vmcnt(4)" ::: "memory");
        } else {
            asm volatile("s_waitcnt vmcnt(0)" ::: "memory");
        }
        asm volatile("s_barrier" ::: "memory");
        const char* Ab = As + cur*8192;
        const char* Bb = Bs + cur*8192;
        bf16x8v af[4], bfr[4];
        #pragma unroll
        for (int i = 0; i < 4; ++i) af[i]  = frag32(Ab, wr + i*16 + fr, fg << 4);
        #pragma unroll
        for (int i = 0; i < 4; ++i) bfr[i] = frag32(Bb, wc + i*16 + fr, fg << 4);
        #pragma unroll
        for (int i = 0; i < 4; ++i)
        #pragma unroll
        for (int j = 0; j < 4; ++j)
            acc[i][j] = __builtin_amdgcn_mfma_f32_16x16x32_bf16(bfr[i], af[j], acc[i][j], 0, 0, 0);
        asm volatile("s_barrier" ::: "memory");
    }
#undef STAGE_QKV

    const int t_ = jb / 3;                    // 0:q 1:k 2:v
    const int pj = jb - t_*3;
    const int c  = pj*2 + (wc >> 6);          // head 0..5
    const size_t hbase = (size_t)t_*PLANE + (((size_t)(n*NH + c)*HEADPIX) << 6);

    if (t_ < 2) {
        // fused L2-norm * sqrt(scale) + rotary; pair dims: e=fg*4+r (i=0) <-> e+16 (i=1)
        const float sq = sqrtf(scale[c]);
        const float4 f4 = *(const float4*)(freqs + c*8 + ((fg & 1) << 2));
        float fqv[4] = {f4.x, f4.y, f4.z, f4.w};
        #pragma unroll
        for (int ni = 0; ni < 4; ++ni) {
            int m = m0 + wr + ni*16 + fr;
            float ss = 0.f;
            #pragma unroll
            for (int i = 0; i < 4; ++i)
                #pragma unroll
                for (int r = 0; r < 4; ++r) ss += acc[i][ni][r]*acc[i][ni][r];
            ss += __shfl_xor(ss, 16);
            ss += __shfl_xor(ss, 32);
            float rn = sq * rsqrtf(ss + EPSF);
            float2 pp = *(const float2*)(pos + (size_t)m*2);
            float pc = (fg < 2) ? pp.x : pp.y;
            u16x4 o0, o1, o2, o3;
            #pragma unroll
            for (int r = 0; r < 4; ++r) {
                float th = pc * fqv[r];
                float ct = __cosf(th), st = __sinf(th);
                float a0 = acc[0][ni][r]*rn, a1 = acc[1][ni][r]*rn;
                o0[r] = f2bf(a0*ct - a1*st);
                o1[r] = f2bf(a1*ct + a0*st);
                o2[r] = f2bf(acc[2][ni][r]*rn);
                o3[r] = f2bf(acc[3][ni][r]*rn);
            }
            size_t base = hbase + ((size_t)(m & (HEADPIX-1)) << 6) + (fg << 2);
            *(u16x4*)(qkv + base     ) = o0;
            *(u16x4*)(qkv + base + 16) = o1;
            *(u16x4*)(qkv + base + 32) = o2;
            *(u16x4*)(qkv + base + 48) = o3;
        }
    } else {
        #pragma unroll
        for (int ni = 0; ni < 4; ++ni) {
            int m = m0 + wr + ni*16 + fr;
            size_t base = hbase + ((size_t)(m & (HEADPIX-1)) << 6) + (fg << 2);
            #pragma unroll
            for (int i = 0; i < 4; ++i) {
                u16x4 pk;
                #pragma unroll
                for (int r = 0; r < 4; ++r) pk[r] = f2bf(acc[i][ni][r]);
                *(u16x4*)(qkv + base + i*16) = pk;
            }
        }
    }
}

// ---------------- K5: 7x7 neighborhood attention via MFMA ----------------
// key space = 224 = 14 uh x 16 uw (uw 14,15 are pad cols, auto-masked by window test).
// K staged [224][128B] (xor-swizzled source); V staged via global_load_lds into
// subtiled layout off(key,d) = ((key>>2)*4 + (d>>4))*128 + (key&3)*32 + (d&15)*2,
// consumed by ds_read_b64_tr_b16 with group lanes at subtile_base + fr*8.
// P stored TRANSPOSED in the same subtile scheme, pre-normalized; PV computes
// O^T[d][q] = mfma(V^T-frag, P^T-frag); epilogue stores 4 consecutive d per u16x4.
__global__ __launch_bounds__(256) void k_attn2(
    const __hip_bfloat16* __restrict__ q, const __hip_bfloat16* __restrict__ kbuf,
    const __hip_bfloat16* __restrict__ vbuf, __hip_bfloat16* __restrict__ attn)
{
    __shared__ char smem[61440];   // [0,28672): K rows then P^T subtiles; [32768,61440): V subtiled 28KB
    char* KP = smem;
    char* VT = smem + 32768;

    const int t    = threadIdx.x;
    const int lane = t & 63;
    const int wave = t >> 6;
    const int fr   = lane & 15;
    const int fg   = lane >> 4;

    const int tile = blockIdx.x;          // 0..255 spatial tiles
    const int n6c  = blockIdx.y;          // 0..23
    const int h0 = (tile >> 4) << 3;
    const int w0 = (tile & 15) << 3;
    const int nn = n6c / NH;
    const int cc = n6c - nn*NH;

    const size_t pixbase = (size_t)n6c << 14;
    const __hip_bfloat16* qp = q    + (pixbase << 6);
    const __hip_bfloat16* kp = kbuf + (pixbase << 6);
    const __hip_bfloat16* vp = vbuf + (pixbase << 6);

    const int u0h = min(max(h0-3,0), IMH-7);
    const int u0w = min(max(w0-3,0), IMW-7);

    // ---- stage K rows [224][128B], swizzled global source, linear LDS dest
    #pragma unroll
    for (int it = 0; it < 7; ++it) {
        int chunk = it*256 + t;            // < 1792
        int key  = chunk >> 3;
        int part = chunk & 7;
        int kh = min(u0h + (key >> 4), IMH-1);
        int kw = min(u0w + (key & 15), IMW-1);
        GLOAD_LDS16(kp + (((size_t)kh*IMW + kw) << 6) + ((part ^ (key & 7)) << 3),
                    KP + (it*256 + (wave<<6))*16);
    }
    // ---- stage V subtiled for tr-read: chunk -> (keyq, d4, kq, dhalf)
    #pragma unroll
    for (int it = 0; it < 7; ++it) {
        int chunk = it*256 + t;            // < 1792
        int keyq = chunk >> 5;
        int rem  = chunk & 31;
        int key  = (keyq << 2) + ((rem >> 1) & 3);
        int d0   = ((rem >> 3) << 4) + ((chunk & 1) << 3);
        int kh = min(u0h + (key >> 4), IMH-1);
        int kw = min(u0w + (key & 15), IMW-1);
        GLOAD_LDS16(vp + (((size_t)kh*IMW + kw) << 6) + d0,
                    VT + (it*256 + (wave<<6))*16);
    }
    // ---- Q A-frags direct from global
    const int q_l = (wave<<4) + fr;
    const int qh = h0 + (q_l >> 3), qw = w0 + (q_l & 7);
    const __hip_bfloat16* qrow = qp + (((size_t)qh*IMW + qw) << 6);
    bf16x8v aq0 = *(const bf16x8v*)(qrow + fg*8);
    bf16x8v aq1 = *(const bf16x8v*)(qrow + 32 + fg*8);

    // per-row window starts (local)
    int loh[4], low_[4];
    #pragma unroll
    for (int r = 0; r < 4; ++r) {
        int qr  = (wave<<4) + fg*4 + r;
        int qhr = h0 + (qr >> 3), qwr = w0 + (qr & 7);
        loh[r]  = min(max(qhr-3,0), IMH-7) - u0h;
        low_[r] = min(max(qwr-3,0), IMW-7) - u0w;
    }

    __syncthreads();

    // ---- QK (14 key frags): acc_s[nf][r] = S[q = wave*16+fg*4+r][key = nf*16+fr]
    f32x4v acc_s[14];
    #pragma unroll
    for (int nf = 0; nf < 14; ++nf) {
        bf16x8v b0 = frag8((const __hip_bfloat16*)KP, nf*16 + fr, fg*8);
        bf16x8v b1 = frag8((const __hip_bfloat16*)KP, nf*16 + fr, 32 + fg*8);
        f32x4v s = {0.f,0.f,0.f,0.f};
        s = __builtin_amdgcn_mfma_f32_16x16x32_bf16(aq0, b0, s, 0, 0, 0);
        s = __builtin_amdgcn_mfma_f32_16x16x32_bf16(aq1, b1, s, 0, 0, 0);
        acc_s[nf] = s;
    }

    // ---- mask + exp (no max-sub: |s| <= ~10.3) + row sums
    float rs[4] = {0.f,0.f,0.f,0.f};
    #pragma unroll
    for (int nf = 0; nf < 14; ++nf) {
        int key = nf*16 + fr;
        int uh = key >> 4;
        int uw = key & 15;
        #pragma unroll
        for (int r = 0; r < 4; ++r) {
            bool ok = ((unsigned)(uh - loh[r]) <= 6u) && ((unsigned)(uw - low_[r]) <= 6u);
            float pv = ok ? __expf(acc_s[nf][r]) : 0.f;
            acc_s[nf][r] = pv;
            rs[r] += pv;
        }
    }
    #pragma unroll
    for (int o = 1; o < 16; o <<= 1) {
        #pragma unroll
        for (int r = 0; r < 4; ++r) rs[r] += __shfl_xor(rs[r], o);
    }
    float rinv[4];
    #pragma unroll
    for (int r = 0; r < 4; ++r) rinv[r] = 1.0f / rs[r];

    __syncthreads();   // all waves done reading K before P^T overwrites it

    // ---- write normalized P^T (bf16) into KP as [keyq][qq] subtiles; 4 consecutive q per write.
    //      Each wave writes only its own qq=wave subtiles -> no cross-wave barrier needed after.
    #pragma unroll
    for (int nf = 0; nf < 14; ++nf) {
        int key = nf*16 + fr;
        u16x4 pk;
        #pragma unroll
        for (int r = 0; r < 4; ++r) pk[r] = f2bf(acc_s[nf][r] * rinv[r]);
        *(u16x4*)(KP + (((key >> 2) << 2) + wave)*128 + ((key & 3) << 5) + (fg << 3)) = pk;
    }
    asm volatile("s_waitcnt lgkmcnt(0)" ::: "memory");
    __builtin_amdgcn_sched_barrier(0);

    // ---- PV: O^T[d][q] += V^T-frag x P^T-frag, both via tr-reads
    //      acc_o[nf]: d = cc*64 + nf*16 + fg*4 + r, qcol = wave*16 + fr
    f32x4v acc_o[4] = {};
    const char* vlane = VT + (fg << 10) + (fr << 3);
    const char* plbase = KP + (wave << 7) + (fr << 3);
    #pragma unroll
    for (int kst = 0; kst < 7; ++kst) {
        const char* vk = vlane + kst*4096;
        const char* pk_ = plbase + (((kst << 3) + (fg << 1)) << 9);   // (kst*8+fg*2)*512
        bf16x4v pa, pb;
        TR64(pa, pk_, 0); TR64(pb, pk_, 512);
        bf16x4v t0a, t0b, t1a, t1b, t2a, t2b, t3a, t3b;
        TR64(t0a, vk,   0); TR64(t0b, vk, 512);
        TR64(t1a, vk, 128); TR64(t1b, vk, 640);
        TR64(t2a, vk, 256); TR64(t2b, vk, 768);
        TR64(t3a, vk, 384); TR64(t3b, vk, 896);
        asm volatile("s_waitcnt lgkmcnt(0)" ::: "memory");
        __builtin_amdgcn_sched_barrier(0);
        bf16x8v pfrag = cat8(pa, pb);
        acc_o[0] = __builtin_amdgcn_mfma_f32_16x16x32_bf16(cat8(t0a,t0b), pfrag, acc_o[0], 0, 0, 0);
        acc_o[1] = __builtin_amdgcn_mfma_f32_16x16x32_bf16(cat8(t1a,t1b), pfrag, acc_o[1], 0, 0, 0);
        acc_o[2] = __builtin_amdgcn_mfma_f32_16x16x32_bf16(cat8(t2a,t2b), pfrag, acc_o[2], 0, 0, 0);
        acc_o[3] = __builtin_amdgcn_mfma_f32_16x16x32_bf16(cat8(t3a,t3b), pfrag, acc_o[3], 0, 0, 0);
    }

    // ---- epilogue: pack 4 consecutive d per store (already normalized)
    {
        int qr  = (wave<<4) + fr;
        int qhr = h0 + (qr >> 3), qwr = w0 + (qr & 7);
        size_t pixo = (((size_t)nn << 14) + (size_t)qhr*IMW + qwr)*DM + cc*64 + (fg << 2);
        #pragma unroll
        for (int nf = 0; nf < 4; ++nf) {
            u16x4 ov;
            #pragma unroll
            for (int r = 0; r < 4; ++r) ov[r] = f2bf(acc_o[nf][r]);
            *(u16x4*)(attn + pixo + nf*16) = ov;
        }
    }
}

// ---------------- K6: out = attn @ w_out + x via bf16 MFMA (transposed C) ----------------
// BK=32 double-buffered, 32 KB LDS (same scheme as k_qkv_mfma).
__global__ __launch_bounds__(256) void k_out_mfma(
    const __hip_bfloat16* __restrict__ attn, const __hip_bfloat16* __restrict__ wob,
    const float* __restrict__ xin, float* __restrict__ out)
{
    __shared__ char As[2*8192];
    __shared__ char Bs[2*8192];
    const int t    = threadIdx.x;
    const int lane = t & 63;
    const int wave = t >> 6;
    // XCD-bijective swizzle: 1536 blocks = 8 x 192; j fastest within chunk
    const int swzb = (blockIdx.x & 7)*192 + (blockIdx.x >> 3);
    const int jb = swzb % 3;
    const int mb = swzb / 3;
    const int j0 = jb*128, m0 = mb*128;
    const int wr = (wave >> 1) * 64;
    const int wc = (wave & 1) * 64;
    const int fr = lane & 15;
    const int fg = lane >> 4;

    f32x4v acc[4][4] = {};

#define STAGE_OUT(buf, k0) \
    { _Pragma("unroll") \
      for (int i = 0; i < 2; ++i) { \
        int ch  = i*256 + t; \
        int row = ch >> 2; \
        int sc_ = ((ch & 3) ^ ((row >> 1) & 3)) << 3; \
        GLOAD_LDS16(attn + (size_t)(m0 + row)*DM + (k0) + sc_, \
                    As + (buf)*8192 + (i*256 + (wave<<6))*16); \
        GLOAD_LDS16(wob  + (size_t)(j0 + row)*DM + (k0) + sc_, \
                    Bs + (buf)*8192 + (i*256 + (wave<<6))*16); \
      } }

    STAGE_OUT(0, 0)
    #pragma unroll
    for (int kt = 0; kt < 12; ++kt) {
        const int cur = kt & 1;
        if (kt < 11) {
            STAGE_OUT(cur ^ 1, (kt+1)*32)
            asm volatile("s_waitcnt vmcnt(4)" ::: "memory");
        } else {
            asm volatile("s_waitcnt vmcnt(0)" ::: "memory");
        }
        asm volatile("s_barrier" ::: "memory");
        const char* Ab = As + cur*8192;
        const char* Bb = Bs + cur*8192;
        bf16x8v af[4], bfr[4];
        #pragma unroll
        for (int i = 0; i < 4; ++i) af[i]  = frag32(Ab, wr + i*16 + fr, fg << 4);
        #pragma unroll
        for (int i = 0; i < 4; ++i) bfr[i] = frag32(Bb, wc + i*16 + fr, fg << 4);
        #pragma unroll
        for (int i = 0; i < 4; ++i)
        #pragma unroll
        for (int j = 0; j < 4; ++j)
            acc[i][j] = __builtin_amdgcn_mfma_f32_16x16x32_bf16(bfr[i], af[j], acc[i][j], 0, 0, 0);
        asm volatile("s_barrier" ::: "memory");
    }
#undef STAGE_OUT

    // acc[i][ni]: row j = j0+wc+i*16+fg*4+r (out dim), col m = m0+wr+ni*16+fr (pixel)
    #pragma unroll
    for (int i = 0; i < 4; ++i) {
        int jg = j0 + wc + i*16 + (fg<<2);
        #pragma unroll
        for (int ni = 0; ni < 4; ++ni) {
            int m = m0 + wr + ni*16 + fr;
            size_t idx = (size_t)m*DM + jg;
            float4 xv = *(const float4*)(xin + idx);
            float4 ov;
            ov.x = acc[i][ni][0] + xv.x;
            ov.y = acc[i][ni][1] + xv.y;
            ov.z = acc[i][ni][2] + xv.z;
            ov.w = acc[i][ni][3] + xv.w;
            *(float4*)(out + idx) = ov;
        }
    }
}

extern "C" void kernel_launch(void* const* d_in, const int* in_sizes, int n_in,
                              void* d_out, int out_size, void* d_ws, size_t ws_size,
                              hipStream_t stream) {
    const float* x      = (const float*)d_in[0];
    const float* pos    = (const float*)d_in[1];
    const float* cond   = (const float*)d_in[2];
    const float* w_cond = (const float*)d_in[3];
    const float* w_qkv  = (const float*)d_in[4];
    const float* scale  = (const float*)d_in[5];
    const float* freqs  = (const float*)d_in[6];
    const float* w_out  = (const float*)d_in[7];
    float* out = (float*)d_out;

    // ws layout (peak 202,217,472 B):
    //   [0, 50331648):            xb (bf16 PLANE) early; attn (bf16 PLANE) late (xb dead)
    //   [50331648, 201326592):    q/k/v planes; q-plane head reused for wob after k_attn2
    //   [201326592, 201332736):   s_cond
    //   [201332736, 202217472):   wqb (bf16 w_qkv^T)
    char* ws = (char*)d_ws;
    __hip_bfloat16* xb   = (__hip_bfloat16*)ws;
    __hip_bfloat16* attn = (__hip_bfloat16*)ws;
    __hip_bfloat16* qkv  = (__hip_bfloat16*)(ws + 50331648);
    float* s_cond = (float*)(ws + 201326592);
    __hip_bfloat16* wqb = (__hip_bfloat16*)(ws + 201332736);
    __hip_bfloat16* qb = qkv;
    __hip_bfloat16* kb = qkv + PLANE;
    __hip_bfloat16* vb = qkv + 2*PLANE;
    __hip_bfloat16* wob = qkv;   // reuse dead q-plane after k_attn2

    k_cvtwq<<<1728, 256, 0, stream>>>(w_qkv, wqb);
    k_cond<<<24, 256, 0, stream>>>(cond, w_cond, s_cond);
    k_xscale<<<NPIX/4, 256, 0, stream>>>(x, s_cond, xb);
    k_qkv_mfma<<<4608, 256, 0, stream>>>(xb, wqb, pos, freqs, scale, qkv);
    k_attn2<<<dim3(256, 24), 256, 0, stream>>>(qb, kb, vb, attn);
    k_cvtwo<<<576, 256, 0, stream>>>(w_out, wob);
    k_out_mfma<<<1536, 256, 0, stream>>>(attn, wob, x, out);
}

// Round 8
// 276.797 us; speedup vs baseline: 1.1182x; 1.1182x over previous
//
#include <hip/hip_runtime.h>
#include <hip/hip_bf16.h>

#define DM 384
#define NH 6
#define DH 64
#define CD 768
#define NBATCH 4
#define IMH 128
#define IMW 128
#define HEADPIX (IMH*IMW)          // 16384
#define NPIX (NBATCH*IMH*IMW)      // 65536
#define PLANE ((size_t)NPIX*DM)    // 25165824 elements per q/k/v plane
#define KS 7
#define EPSF 1e-6f

typedef __attribute__((ext_vector_type(8))) short bf16x8v;
typedef __attribute__((ext_vector_type(4))) short bf16x4v;
typedef __attribute__((ext_vector_type(4))) float f32x4v;
typedef __attribute__((ext_vector_type(4))) unsigned short u16x4;

#define GLOAD_LDS16(g, l) __builtin_amdgcn_global_load_lds( \
    (const __attribute__((address_space(1))) void*)(g), \
    (__attribute__((address_space(3))) void*)(l), 16, 0, 0)

// hardware transpose read of a 4x16-bf16 subtile: group lanes at base+fr*8,
// lane fr elem j <- tile[row j][col fr]   (verified on HW in R4)
#define TR64(dst, p, imm) asm volatile("ds_read_b64_tr_b16 %0, %1 offset:" #imm \
    : "=v"(dst) : "v"((const __attribute__((address_space(3))) char*)(p)))

__device__ __forceinline__ unsigned short f2bf(float f){
    __hip_bfloat16 h = __float2bfloat16(f);
    return *reinterpret_cast<unsigned short*>(&h);
}
__device__ __forceinline__ bf16x8v cat8(bf16x4v lo, bf16x4v hi){
    bf16x8v r;
    r[0]=lo[0]; r[1]=lo[1]; r[2]=lo[2]; r[3]=lo[3];
    r[4]=hi[0]; r[5]=hi[1]; r[6]=hi[2]; r[7]=hi[3];
    return r;
}

// swizzled LDS fragment reads: tile stored [row][stride], byte col ^= (row&7)<<4
__device__ __forceinline__ bf16x8v frag8(const __hip_bfloat16* base, int row, int kelem){
    int byteoff = row*128 + ((kelem*2) ^ ((row & 7) << 4));
    return *(const bf16x8v*)((const char*)base + byteoff);
}
__device__ __forceinline__ bf16x8v frag512(const char* base, int row, int kelem){
    int byteoff = row*512 + ((kelem*2) ^ ((row & 7) << 4));
    return *(const bf16x8v*)(base + byteoff);
}

// ---------------- K1: s_cond = cond @ w_cond + 1 (split-K over 4 waves) ----------------
__global__ __launch_bounds__(256) void k_cond(const float* __restrict__ cond,
                                              const float* __restrict__ wc,
                                              float* __restrict__ sc){
    __shared__ float red[4][64];
    const int b = blockIdx.x;           // 24 = 4 n * 6 j-chunks
    const int n = b / 6, j0 = (b - n*6) * 64;
    const int lane = threadIdx.x & 63, wave = threadIdx.x >> 6;
    const float* cr = cond + n*CD + wave*192;
    const float* wp = wc + (size_t)(wave*192)*DM + j0 + lane;
    float acc = 0.f;
    #pragma unroll 4
    for (int i = 0; i < 192; ++i) acc += cr[i] * wp[(size_t)i*DM];
    red[wave][lane] = acc;
    __syncthreads();
    if (threadIdx.x < 64) {
        float s = red[0][lane] + red[1][lane] + red[2][lane] + red[3][lane];
        sc[n*DM + j0 + lane] = s + 1.0f;
    }
}

// ---------------- K2: xb = bf16(x * rsqrt(mean(x^2)+eps) * s_cond) ----------------
__global__ __launch_bounds__(256) void k_xscale(const float* __restrict__ x,
                                                const float* __restrict__ sc,
                                                __hip_bfloat16* __restrict__ xb){
    int row  = blockIdx.x*4 + (threadIdx.x>>6);
    int lane = threadIdx.x & 63;
    int n    = row >> 14;
    const float* xr  = x + (size_t)row*DM;
    const float* scp = sc + n*DM;
    float v[6];
    float s = 0.f;
    #pragma unroll
    for (int i=0;i<6;++i){ v[i] = xr[i*64+lane]; s += v[i]*v[i]; }
    #pragma unroll
    for (int o=32;o;o>>=1) s += __shfl_xor(s,o);
    float r = rsqrtf(s*(1.0f/DM) + EPSF);
    #pragma unroll
    for (int i=0;i<6;++i)
        xb[(size_t)row*DM + i*64+lane] = __float2bfloat16(v[i]*r*scp[i*64+lane]);
}

// ---------------- weight converts: bf16, transposed to [N][K] ----------------
__global__ void k_cvtwq(const float* __restrict__ wq, __hip_bfloat16* __restrict__ wqb){
    int id = blockIdx.x*256 + threadIdx.x;          // 1152*384
    if (id >= 3*DM*DM) return;
    int nn = id / DM, kk = id - nn*DM;
    wqb[id] = __float2bfloat16(wq[(size_t)kk*(3*DM) + nn]);
}
__global__ void k_cvtwo(const float* __restrict__ wo, __hip_bfloat16* __restrict__ wob){
    int id = blockIdx.x*256 + threadIdx.x;          // 384*384
    if (id >= DM*DM) return;
    int nn = id / DM, kk = id - nn*DM;
    wob[id] = __float2bfloat16(wo[(size_t)kk*DM + nn]);
}

// ---------------- K3: qkv = xb @ w_qkv via bf16 MFMA (transposed C); fused qk-norm + rotary ----------------
// R4-proven structure: A and B double-buffered in LDS, 2-phase counted vmcnt.
// acc[i][ni]: output ROW = weight col j = j0 + wc + i*16 + fg*4 + r (dim),
//             output COL = pixel     m = m0 + wr + ni*16 + fr
__global__ __launch_bounds__(256) void k_qkv_mfma(
    const __hip_bfloat16* __restrict__ xb, const __hip_bfloat16* __restrict__ wqb,
    const float* __restrict__ pos, const float* __restrict__ freqs,
    const float* __restrict__ scale, __hip_bfloat16* __restrict__ qkv)
{
    __shared__ char As[2*16384];
    __shared__ char Bs[2*16384];
    const int t    = threadIdx.x;
    const int lane = t & 63;
    const int wave = t >> 6;
    // XCD-bijective swizzle: 4608 blocks = 8 XCDs x 576; j fastest within chunk
    const int swzb = (blockIdx.x & 7)*576 + (blockIdx.x >> 3);
    const int jb = swzb % 9;
    const int mb = swzb / 9;
    const int j0 = jb*128, m0 = mb*128;
    const int n  = m0 >> 14;
    const int wr = (wave >> 1) * 64;
    const int wc = (wave & 1) * 64;
    const int fr = lane & 15;
    const int fg = lane >> 4;

    f32x4v acc[4][4] = {};

#define STAGE_QKV(buf, k0) \
    { _Pragma("unroll") \
      for (int i = 0; i < 4; ++i) { \
        int off = (i*256 + t) * 8; \
        int row = off >> 6; \
        int col = (off & 63) ^ ((row & 7) << 3); \
        GLOAD_LDS16(xb  + (size_t)(m0 + row)*DM + (k0) + col, \
                    As + (buf)*16384 + (i*256 + (wave<<6))*16); \
        GLOAD_LDS16(wqb + (size_t)(j0 + row)*DM + (k0) + col, \
                    Bs + (buf)*16384 + (i*256 + (wave<<6))*16); \
      } }

    // 2-phase pipeline: stage(next) -> counted vmcnt -> barrier -> compute(cur) -> barrier
    STAGE_QKV(0, 0)
    #pragma unroll
    for (int kt = 0; kt < 6; ++kt) {
        const int cur = kt & 1;
        if (kt < 5) {
            STAGE_QKV(cur ^ 1, (kt+1)*64)
            asm volatile("s_waitcnt vmcnt(8)" ::: "memory");
        } else {
            asm volatile("s_waitcnt vmcnt(0)" ::: "memory");
        }
        asm volatile("s_barrier" ::: "memory");
        const __hip_bfloat16* Ab = (const __hip_bfloat16*)(As + cur*16384);
        const __hip_bfloat16* Bb = (const __hip_bfloat16*)(Bs + cur*16384);
        #pragma unroll
        for (int kk = 0; kk < 64; kk += 32) {
            bf16x8v af[4], bfr[4];
            #pragma unroll
            for (int i = 0; i < 4; ++i) af[i]  = frag8(Ab, wr + i*16 + fr, kk + fg*8);
            #pragma unroll
            for (int i = 0; i < 4; ++i) bfr[i] = frag8(Bb, wc + i*16 + fr, kk + fg*8);
            #pragma unroll
            for (int i = 0; i < 4; ++i)
            #pragma unroll
            for (int j = 0; j < 4; ++j)
                acc[i][j] = __builtin_amdgcn_mfma_f32_16x16x32_bf16(bfr[i], af[j], acc[i][j], 0, 0, 0);
        }
        asm volatile("s_barrier" ::: "memory");
    }
#undef STAGE_QKV

    const int t_ = jb / 3;                    // 0:q 1:k 2:v
    const int pj = jb - t_*3;
    const int c  = pj*2 + (wc >> 6);          // head 0..5
    const size_t hbase = (size_t)t_*PLANE + (((size_t)(n*NH + c)*HEADPIX) << 6);

    if (t_ < 2) {
        // fused L2-norm * sqrt(scale) + rotary; pair dims: e=fg*4+r (i=0) <-> e+16 (i=1)
        const float sq = sqrtf(scale[c]);
        const float4 f4 = *(const float4*)(freqs + c*8 + ((fg & 1) << 2));
        float fqv[4] = {f4.x, f4.y, f4.z, f4.w};
        #pragma unroll
        for (int ni = 0; ni < 4; ++ni) {
            int m = m0 + wr + ni*16 + fr;
            float ss = 0.f;
            #pragma unroll
            for (int i = 0; i < 4; ++i)
                #pragma unroll
                for (int r = 0; r < 4; ++r) ss += acc[i][ni][r]*acc[i][ni][r];
            ss += __shfl_xor(ss, 16);
            ss += __shfl_xor(ss, 32);
            float rn = sq * rsqrtf(ss + EPSF);
            float2 pp = *(const float2*)(pos + (size_t)m*2);
            float pc = (fg < 2) ? pp.x : pp.y;
            u16x4 o0, o1, o2, o3;
            #pragma unroll
            for (int r = 0; r < 4; ++r) {
                float th = pc * fqv[r];
                float ct = __cosf(th), st = __sinf(th);
                float a0 = acc[0][ni][r]*rn, a1 = acc[1][ni][r]*rn;
                o0[r] = f2bf(a0*ct - a1*st);
                o1[r] = f2bf(a1*ct + a0*st);
                o2[r] = f2bf(acc[2][ni][r]*rn);
                o3[r] = f2bf(acc[3][ni][r]*rn);
            }
            size_t base = hbase + ((size_t)(m & (HEADPIX-1)) << 6) + (fg << 2);
            *(u16x4*)(qkv + base     ) = o0;
            *(u16x4*)(qkv + base + 16) = o1;
            *(u16x4*)(qkv + base + 32) = o2;
            *(u16x4*)(qkv + base + 48) = o3;
        }
    } else {
        #pragma unroll
        for (int ni = 0; ni < 4; ++ni) {
            int m = m0 + wr + ni*16 + fr;
            size_t base = hbase + ((size_t)(m & (HEADPIX-1)) << 6) + (fg << 2);
            #pragma unroll
            for (int i = 0; i < 4; ++i) {
                u16x4 pk;
                #pragma unroll
                for (int r = 0; r < 4; ++r) pk[r] = f2bf(acc[i][ni][r]);
                *(u16x4*)(qkv + base + i*16) = pk;
            }
        }
    }
}

// ---------------- K5: 7x7 neighborhood attention via MFMA ----------------
// key space = 224 = 14 uh x 16 uw (uw 14,15 are pad cols, auto-masked by window test).
// Counted-wait staging (m218 pattern): Q-reg loads issue FIRST (oldest), then K's 7
// global_load_lds, then V's 7; wave waits vmcnt(7) (Q+K resident, V in flight) before
// the barrier, so V's HBM latency hides under QK^T + softmax; V drained by
// vmcnt(0)+barrier just before PV.
__global__ __launch_bounds__(256) void k_attn2(
    const __hip_bfloat16* __restrict__ q, const __hip_bfloat16* __restrict__ kbuf,
    const __hip_bfloat16* __restrict__ vbuf, __hip_bfloat16* __restrict__ attn)
{
    __shared__ char smem[61440];   // [0,32768): K rows(224x128B) then P(64x512B); [32768,61440): V subtiled 28KB
    char* KP = smem;
    char* VT = smem + 32768;

    const int t    = threadIdx.x;
    const int lane = t & 63;
    const int wave = t >> 6;
    const int fr   = lane & 15;
    const int fg   = lane >> 4;

    const int tile = blockIdx.x;          // 0..255 spatial tiles
    const int n6c  = blockIdx.y;          // 0..23
    const int h0 = (tile >> 4) << 3;
    const int w0 = (tile & 15) << 3;
    const int nn = n6c / NH;
    const int cc = n6c - nn*NH;

    const size_t pixbase = (size_t)n6c << 14;
    const __hip_bfloat16* qp = q    + (pixbase << 6);
    const __hip_bfloat16* kp = kbuf + (pixbase << 6);
    const __hip_bfloat16* vp = vbuf + (pixbase << 6);

    const int u0h = min(max(h0-3,0), IMH-7);
    const int u0w = min(max(w0-3,0), IMW-7);

    // ---- Q A-frags FIRST (oldest vmem ops -> covered by the counted wait)
    const int q_l = (wave<<4) + fr;
    const int qh = h0 + (q_l >> 3), qw = w0 + (q_l & 7);
    const __hip_bfloat16* qrow = qp + (((size_t)qh*IMW + qw) << 6);
    bf16x8v aq0 = *(const bf16x8v*)(qrow + fg*8);
    bf16x8v aq1 = *(const bf16x8v*)(qrow + 32 + fg*8);
    __builtin_amdgcn_sched_barrier(0);   // pin Q loads before the staging issues

    // ---- stage K rows [224][128B], swizzled global source, linear LDS dest (7 loads)
    #pragma unroll
    for (int it = 0; it < 7; ++it) {
        int chunk = it*256 + t;            // < 1792
        int key  = chunk >> 3;
        int part = chunk & 7;
        int kh = min(u0h + (key >> 4), IMH-1);
        int kw = min(u0w + (key & 15), IMW-1);
        GLOAD_LDS16(kp + (((size_t)kh*IMW + kw) << 6) + ((part ^ (key & 7)) << 3),
                    KP + (it*256 + (wave<<6))*16);
    }
    // ---- stage V subtiled for tr-read (7 loads, newest -> left in flight)
    #pragma unroll
    for (int it = 0; it < 7; ++it) {
        int chunk = it*256 + t;            // < 1792
        int keyq = chunk >> 5;
        int rem  = chunk & 31;
        int key  = (keyq << 2) + ((rem >> 1) & 3);
        int d0   = ((rem >> 3) << 4) + ((chunk & 1) << 3);
        int kh = min(u0h + (key >> 4), IMH-1);
        int kw = min(u0w + (key & 15), IMW-1);
        GLOAD_LDS16(vp + (((size_t)kh*IMW + kw) << 6) + d0,
                    VT + (it*256 + (wave<<6))*16);
    }

    // per-row window starts (local)
    int loh[4], low_[4];
    #pragma unroll
    for (int r = 0; r < 4; ++r) {
        int qr  = (wave<<4) + fg*4 + r;
        int qhr = h0 + (qr >> 3), qwr = w0 + (qr & 7);
        loh[r]  = min(max(qhr-3,0), IMH-7) - u0h;
        low_[r] = min(max(qwr-3,0), IMW-7) - u0w;
    }

    // Q + K resident for every wave crossing the barrier; V's 7 loads stay in flight.
    asm volatile("s_waitcnt vmcnt(7)" ::: "memory");
    asm volatile("s_barrier" ::: "memory");

    // ---- QK (14 key frags): acc_s[nf][r] = S[q = wave*16+fg*4+r][key = nf*16+fr]
    f32x4v acc_s[14];
    #pragma unroll
    for (int nf = 0; nf < 14; ++nf) {
        bf16x8v b0 = frag8((const __hip_bfloat16*)KP, nf*16 + fr, fg*8);
        bf16x8v b1 = frag8((const __hip_bfloat16*)KP, nf*16 + fr, 32 + fg*8);
        f32x4v s = {0.f,0.f,0.f,0.f};
        s = __builtin_amdgcn_mfma_f32_16x16x32_bf16(aq0, b0, s, 0, 0, 0);
        s = __builtin_amdgcn_mfma_f32_16x16x32_bf16(aq1, b1, s, 0, 0, 0);
        acc_s[nf] = s;
    }

    // ---- mask + exp (no max-sub: |s| <= ~10.3) + row sums
    float rs[4] = {0.f,0.f,0.f,0.f};
    #pragma unroll
    for (int nf = 0; nf < 14; ++nf) {
        int key = nf*16 + fr;
        int uh = key >> 4;
        int uw = key & 15;
        #pragma unroll
        for (int r = 0; r < 4; ++r) {
            bool ok = ((unsigned)(uh - loh[r]) <= 6u) && ((unsigned)(uw - low_[r]) <= 6u);
            float pv = ok ? __expf(acc_s[nf][r]) : 0.f;
            acc_s[nf][r] = pv;
            rs[r] += pv;
        }
    }
    #pragma unroll
    for (int o = 1; o < 16; o <<= 1) {
        #pragma unroll
        for (int r = 0; r < 4; ++r) rs[r] += __shfl_xor(rs[r], o);
    }
    float rinv[4];
    #pragma unroll
    for (int r = 0; r < 4; ++r) rinv[r] = 1.0f / rs[r];

    // all waves done reading K before P overwrites it
    asm volatile("s_barrier" ::: "memory");

    // ---- write P (bf16) into KP as [64 q][512B] (own-wave rows only)
    #pragma unroll
    for (int nf = 0; nf < 14; ++nf) {
        int key = nf*16 + fr;
        #pragma unroll
        for (int r = 0; r < 4; ++r) {
            int qr = (wave<<4) + fg*4 + r;
            *(__hip_bfloat16*)(KP + qr*512 + ((key*2) ^ ((qr & 7) << 4))) = __float2bfloat16(acc_s[nf][r]);
        }
    }
    // drain V (free by now) + own P writes; barrier publishes everyone's V
    asm volatile("s_waitcnt vmcnt(0) lgkmcnt(0)" ::: "memory");
    asm volatile("s_barrier" ::: "memory");
    __builtin_amdgcn_sched_barrier(0);

    // ---- PV via hardware transpose reads of V (lane addr = subtile base + fr*8)
    f32x4v acc_o[4] = {};
    const char* vlane = VT + ((lane >> 4) << 10) + ((lane & 15) << 3);
    #pragma unroll
    for (int kst = 0; kst < 7; ++kst) {
        bf16x8v a = frag512(KP, (wave<<4) + fr, kst*32 + fg*8);
        const char* vk = vlane + kst*4096;
        bf16x4v t0a, t0b, t1a, t1b, t2a, t2b, t3a, t3b;
        TR64(t0a, vk,   0); TR64(t0b, vk, 512);
        TR64(t1a, vk, 128); TR64(t1b, vk, 640);
        TR64(t2a, vk, 256); TR64(t2b, vk, 768);
        TR64(t3a, vk, 384); TR64(t3b, vk, 896);
        asm volatile("s_waitcnt lgkmcnt(0)" ::: "memory");
        __builtin_amdgcn_sched_barrier(0);
        acc_o[0] = __builtin_amdgcn_mfma_f32_16x16x32_bf16(a, cat8(t0a,t0b), acc_o[0], 0, 0, 0);
        acc_o[1] = __builtin_amdgcn_mfma_f32_16x16x32_bf16(a, cat8(t1a,t1b), acc_o[1], 0, 0, 0);
        acc_o[2] = __builtin_amdgcn_mfma_f32_16x16x32_bf16(a, cat8(t2a,t2b), acc_o[2], 0, 0, 0);
        acc_o[3] = __builtin_amdgcn_mfma_f32_16x16x32_bf16(a, cat8(t3a,t3b), acc_o[3], 0, 0, 0);
    }

    // ---- epilogue: normalize, write attn [pix][DM]
    #pragma unroll
    for (int nf = 0; nf < 4; ++nf) {
        int d = cc*64 + nf*16 + fr;
        #pragma unroll
        for (int r = 0; r < 4; ++r) {
            int qr  = (wave<<4) + fg*4 + r;
            int qhr = h0 + (qr >> 3), qwr = w0 + (qr & 7);
            size_t pix = ((size_t)nn << 14) + (size_t)qhr*IMW + qwr;
            attn[pix*DM + d] = __float2bfloat16(acc_o[nf][r] * rinv[r]);
        }
    }
}

// ---------------- K6: out = attn @ w_out + x via bf16 MFMA (transposed C) ----------------
__global__ __launch_bounds__(256) void k_out_mfma(
    const __hip_bfloat16* __restrict__ attn, const __hip_bfloat16* __restrict__ wob,
    const float* __restrict__ xin, float* __restrict__ out)
{
    __shared__ char As[2*16384];
    __shared__ char Bs[2*16384];
    const int t    = threadIdx.x;
    const int lane = t & 63;
    const int wave = t >> 6;
    // XCD-bijective swizzle: 1536 blocks = 8 x 192; j fastest within chunk
    const int swzb = (blockIdx.x & 7)*192 + (blockIdx.x >> 3);
    const int jb = swzb % 3;
    const int mb = swzb / 3;
    const int j0 = jb*128, m0 = mb*128;
    const int wr = (wave >> 1) * 64;
    const int wc = (wave & 1) * 64;
    const int fr = lane & 15;
    const int fg = lane >> 4;

    f32x4v acc[4][4] = {};

#define STAGE_OUT(buf, k0) \
    { _Pragma("unroll") \
      for (int i = 0; i < 4; ++i) { \
        int off = (i*256 + t) * 8; \
        int row = off >> 6; \
        int col = (off & 63) ^ ((row & 7) << 3); \
        GLOAD_LDS16(attn + (size_t)(m0 + row)*DM + (k0) + col, \
                    As + (buf)*16384 + (i*256 + (wave<<6))*16); \
        GLOAD_LDS16(wob  + (size_t)(j0 + row)*DM + (k0) + col, \
                    Bs + (buf)*16384 + (i*256 + (wave<<6))*16); \
      } }

    STAGE_OUT(0, 0)
    #pragma unroll
    for (int kt = 0; kt < 6; ++kt) {
        const int cur = kt & 1;
        if (kt < 5) {
            STAGE_OUT(cur ^ 1, (kt+1)*64)
            asm volatile("s_waitcnt vmcnt(8)" ::: "memory");
        } else {
            asm volatile("s_waitcnt vmcnt(0)" ::: "memory");
        }
        asm volatile("s_barrier" ::: "memory");
        const __hip_bfloat16* Ab = (const __hip_bfloat16*)(As + cur*16384);
        const __hip_bfloat16* Bb = (const __hip_bfloat16*)(Bs + cur*16384);
        #pragma unroll
        for (int kk = 0; kk < 64; kk += 32) {
            bf16x8v af[4], bfr[4];
            #pragma unroll
            for (int i = 0; i < 4; ++i) af[i]  = frag8(Ab, wr + i*16 + fr, kk + fg*8);
            #pragma unroll
            for (int i = 0; i < 4; ++i) bfr[i] = frag8(Bb, wc + i*16 + fr, kk + fg*8);
            #pragma unroll
            for (int i = 0; i < 4; ++i)
            #pragma unroll
            for (int j = 0; j < 4; ++j)
                acc[i][j] = __builtin_amdgcn_mfma_f32_16x16x32_bf16(bfr[i], af[j], acc[i][j], 0, 0, 0);
        }
        asm volatile("s_barrier" ::: "memory");
    }
#undef STAGE_OUT

    // acc[i][ni]: row j = j0+wc+i*16+fg*4+r (out dim), col m = m0+wr+ni*16+fr (pixel)
    #pragma unroll
    for (int i = 0; i < 4; ++i) {
        int jg = j0 + wc + i*16 + (fg<<2);
        #pragma unroll
        for (int ni = 0; ni < 4; ++ni) {
            int m = m0 + wr + ni*16 + fr;
            size_t idx = (size_t)m*DM + jg;
            float4 xv = *(const float4*)(xin + idx);
            float4 ov;
            ov.x = acc[i][ni][0] + xv.x;
            ov.y = acc[i][ni][1] + xv.y;
            ov.z = acc[i][ni][2] + xv.z;
            ov.w = acc[i][ni][3] + xv.w;
            *(float4*)(out + idx) = ov;
        }
    }
}

extern "C" void kernel_launch(void* const* d_in, const int* in_sizes, int n_in,
                              void* d_out, int out_size, void* d_ws, size_t ws_size,
                              hipStream_t stream) {
    const float* x      = (const float*)d_in[0];
    const float* pos    = (const float*)d_in[1];
    const float* cond   = (const float*)d_in[2];
    const float* w_cond = (const float*)d_in[3];
    const float* w_qkv  = (const float*)d_in[4];
    const float* scale  = (const float*)d_in[5];
    const float* freqs  = (const float*)d_in[6];
    const float* w_out  = (const float*)d_in[7];
    float* out = (float*)d_out;

    // ws layout (peak 202,217,472 B):
    //   [0, 50331648):            xb (bf16 PLANE) early; attn (bf16 PLANE) late (xb dead)
    //   [50331648, 201326592):    q/k/v planes; q-plane head reused for wob after k_attn2
    //   [201326592, 201332736):   s_cond
    //   [201332736, 202217472):   wqb (bf16 w_qkv^T)
    char* ws = (char*)d_ws;
    __hip_bfloat16* xb   = (__hip_bfloat16*)ws;
    __hip_bfloat16* attn = (__hip_bfloat16*)ws;
    __hip_bfloat16* qkv  = (__hip_bfloat16*)(ws + 50331648);
    float* s_cond = (float*)(ws + 201326592);
    __hip_bfloat16* wqb = (__hip_bfloat16*)(ws + 201332736);
    __hip_bfloat16* qb = qkv;
    __hip_bfloat16* kb = qkv + PLANE;
    __hip_bfloat16* vb = qkv + 2*PLANE;
    __hip_bfloat16* wob = qkv;   // reuse dead q-plane after k_attn2

    k_cvtwq<<<1728, 256, 0, stream>>>(w_qkv, wqb);
    k_cond<<<24, 256, 0, stream>>>(cond, w_cond, s_cond);
    k_xscale<<<NPIX/4, 256, 0, stream>>>(x, s_cond, xb);
    k_qkv_mfma<<<4608, 256, 0, stream>>>(xb, wqb, pos, freqs, scale, qkv);
    k_attn2<<<dim3(256, 24), 256, 0, stream>>>(qb, kb, vb, attn);
    k_cvtwo<<<576, 256, 0, stream>>>(w_out, wob);
    k_out_mfma<<<1536, 256, 0, stream>>>(attn, wob, x, out);
}